// Round 11
// baseline (511.653 us; speedup 1.0000x reference)
//
#include <hip/hip_runtime.h>
#include <hip/hip_bf16.h>

// Clockwork RNN, hierarchical decomposition + bf16 MFMA GEMMs.
// Round 11: radix-2 fold of the serial scan.
//   h_{2j+1} = A^2 h_{2j-1} + v_j,  v_j = A u_{2j} + u_{2j+1}   (serial, Tm/2)
//   h_{2j}   = A h_{2j-1} + u_{2j}                              (parallel fixup)
// New kernels: k_a2 (A^2 per module, once), k_v (v_j, parallel),
// k_even (even-slot fixup, parallel). k_phase scans A^2 over Tm/2 steps.
// Serial steps: 510 -> 255.

#define TT 256
#define BB 128
#define INW 512
#define HH 128
#define MHW 1024

typedef __bf16 bf16x8 __attribute__((ext_vector_type(8)));
typedef __bf16 bf16x4 __attribute__((ext_vector_type(4)));
typedef float f32x4 __attribute__((ext_vector_type(4)));

__constant__ unsigned int c_hmod_off[8] = {
    0u, 4194304u, 6291456u, 7340032u, 7864320u, 8126464u, 8257536u, 8323072u};

__device__ __forceinline__ int active_thr(int t) {
    int ma = (t == 0) ? 8 : min(__ffs(t), 8);
    return ma * HH;
}

__device__ __forceinline__ unsigned short f2bf(float f) {
    union { float f; unsigned int u; } v{f};
    unsigned int r = v.u + 0x7FFFu + ((v.u >> 16) & 1u);  // RNE
    return (unsigned short)(r >> 16);
}
__device__ __forceinline__ unsigned int pack2(float lo, float hi) {
    return (unsigned int)f2bf(lo) | ((unsigned int)f2bf(hi) << 16);
}
__device__ __forceinline__ float bf2f(unsigned short u) {
    union { unsigned int i; float f; } v;
    v.i = ((unsigned int)u) << 16;
    return v.f;
}

__device__ __forceinline__ void gld_lds16(const float* g, char* l) {
    __builtin_amdgcn_global_load_lds(
        (const __attribute__((address_space(1))) void*)g,
        (__attribute__((address_space(3))) void*)l, 16, 0, 0);
}

#define TILE_B 16384  // one [128 rows][64 k] bf16 tile image in LDS

// Batch-load a [128][64] f32 tile: 8 independent float4 per thread.
__device__ __forceinline__ void stage_load(float4 (&v)[8],
                                           const float* __restrict__ src,
                                           int stride, int tid) {
    int k4 = (tid & 15) * 4;
    int r0 = tid >> 4;
#pragma unroll
    for (int p = 0; p < 8; ++p)
        v[p] = *reinterpret_cast<const float4*>(src + (size_t)(p * 16 + r0) * stride + k4);
}

// Convert + write the staged tile into LDS (bf16, XOR-swizzled rows).
__device__ __forceinline__ void stage_write(char* dst, const float4 (&v)[8], int tid) {
    int k8 = (tid & 15) * 8;
    int r0 = tid >> 4;
#pragma unroll
    for (int p = 0; p < 8; ++p) {
        int row = p * 16 + r0;
        ushort4 b;
        b.x = f2bf(v[p].x); b.y = f2bf(v[p].y);
        b.z = f2bf(v[p].z); b.w = f2bf(v[p].w);
        int off = (row * 128 + k8) ^ ((row & 7) << 4);
        *reinterpret_cast<ushort4*>(dst + off) = b;
    }
}

// bf16-source variants: [128 rows][64 k] tile, row stride HH (ushorts).
__device__ __forceinline__ void stage_load_h16(uint4 (&v)[4],
                                               const unsigned short* __restrict__ src,
                                               int tid) {
    int k16 = (tid & 7) * 8;
    int r0 = tid >> 3;
#pragma unroll
    for (int p = 0; p < 4; ++p)
        v[p] = *reinterpret_cast<const uint4*>(src + (size_t)(p * 32 + r0) * HH + k16);
}
__device__ __forceinline__ void stage_write_h16(char* dst, const uint4 (&v)[4], int tid) {
    int k16 = (tid & 7) * 8;
    int r0 = tid >> 3;
#pragma unroll
    for (int p = 0; p < 4; ++p) {
        int row = p * 32 + r0;
        int off = (row * 128 + k16 * 2) ^ ((row & 7) << 4);
        *reinterpret_cast<uint4*>(dst + off) = v[p];
    }
}

// Read one 16x32 bf16 fragment (8 bf16) from a swizzled bf16 tile.
__device__ __forceinline__ bf16x8 frag_ld(const char* tile, int row, int ks, int lane) {
    int off = (row * 128 + ks * 64 + (lane >> 4) * 16) ^ ((row & 7) << 4);
    return *reinterpret_cast<const bf16x8*>(tile + off);
}

// Read one fragment from a swizzled *f32* tile ([rows][64k] f32, 256B/row)
// and convert to bf16x8 (compiler emits v_cvt_pk_bf16_f32).
__device__ __forceinline__ bf16x8 frag_ld_f32(const char* tile, int row, int ks, int g) {
    int off = ((row << 8) + ks * 128 + g * 32) ^ ((row & 7) << 4);
    f32x4 a = *reinterpret_cast<const f32x4*>(tile + off);
    f32x4 b = *reinterpret_cast<const f32x4*>(tile + (off ^ 16));
    bf16x8 u;
    u[0] = (__bf16)a[0]; u[1] = (__bf16)a[1]; u[2] = (__bf16)a[2]; u[3] = (__bf16)a[3];
    u[4] = (__bf16)b[0]; u[5] = (__bf16)b[1]; u[6] = (__bf16)b[2]; u[7] = (__bf16)b[3];
    return u;
}

// 128x128x64 MFMA block: A-tile x B-tile -> acc (4 waves, 64x64 quadrants)
__device__ __forceinline__ void mfma_tile(const char* sA, const char* sB,
                                          f32x4 (&acc)[4][4], int lane,
                                          int wr, int wc) {
#pragma unroll
    for (int ks = 0; ks < 2; ++ks) {
        bf16x8 fa[4], fb[4];
#pragma unroll
        for (int i = 0; i < 4; ++i) {
            fa[i] = frag_ld(sA, wr + i * 16 + (lane & 15), ks, lane);
            fb[i] = frag_ld(sB, wc + i * 16 + (lane & 15), ks, lane);
        }
#pragma unroll
        for (int i = 0; i < 4; ++i)
#pragma unroll
            for (int j = 0; j < 4; ++j)
                acc[i][j] = __builtin_amdgcn_mfma_f32_16x16x32_bf16(
                    fa[i], fb[j], acc[i][j], 0, 0, 0);
    }
}

// ---------------------------------------------------------------------------
// K_xw v3 (unchanged from R10): 1020 uniform blocks, gld_lds f32 staging.
// ---------------------------------------------------------------------------
__global__ __launch_bounds__(256) void k_xw(const float* __restrict__ x,
                                            const float* __restrict__ Wxh,
                                            const float* __restrict__ bh,
                                            float* __restrict__ xwb) {
    __shared__ char ldsW[2][32768];
    __shared__ char ldsX[2][16384];
    int id = blockIdx.x >> 1, half = blockIdx.x & 1;
    int rt = 0, rem = id;
    while (rem >= (256 >> rt)) { rem -= 256 >> rt; ++rt; }
    int t = rem << rt;

    int tid = threadIdx.x, lane = tid & 63, wid = tid >> 6;
    int l15 = lane & 15, g = lane >> 4;
    int wr = (wid >> 1) * 64, wc = (wid & 1) * 32;

    const float* gW[8];
    const float* gX[4];
    {
        int kb = (lane & 15) * 16;
#pragma unroll
        for (int i = 0; i < 8; ++i) {
            int row = i * 16 + wid * 4 + (lane >> 4);
            int kf = (kb ^ ((row & 7) << 4)) >> 2;
            gW[i] = Wxh + (size_t)(rt * 128 + row) * INW + kf;
        }
#pragma unroll
        for (int i = 0; i < 4; ++i) {
            int row = i * 16 + wid * 4 + (lane >> 4);
            int kf = (kb ^ ((row & 7) << 4)) >> 2;
            gX[i] = x + ((size_t)t * BB + half * 64 + row) * INW + kf;
        }
    }
#pragma unroll
    for (int i = 0; i < 8; ++i)
        gld_lds16(gW[i], &ldsW[0][0] + i * 4096 + wid * 1024);
#pragma unroll
    for (int i = 0; i < 4; ++i)
        gld_lds16(gX[i], &ldsX[0][0] + i * 4096 + wid * 1024);

    f32x4 acc[4][2] = {};
    for (int c = 0; c < 8; ++c) {
        int cur = c & 1;
        __syncthreads();
        if (c < 7) {
#pragma unroll
            for (int i = 0; i < 8; ++i)
                gld_lds16(gW[i] + (c + 1) * 64,
                          &ldsW[cur ^ 1][0] + i * 4096 + wid * 1024);
#pragma unroll
            for (int i = 0; i < 4; ++i)
                gld_lds16(gX[i] + (c + 1) * 64,
                          &ldsX[cur ^ 1][0] + i * 4096 + wid * 1024);
        }
#pragma unroll
        for (int ks = 0; ks < 2; ++ks) {
            bf16x8 fa[4], fb[2];
#pragma unroll
            for (int i = 0; i < 4; ++i)
                fa[i] = frag_ld_f32(&ldsW[cur][0], wr + i * 16 + l15, ks, g);
#pragma unroll
            for (int j = 0; j < 2; ++j)
                fb[j] = frag_ld_f32(&ldsX[cur][0], wc + j * 16 + l15, ks, g);
#pragma unroll
            for (int i = 0; i < 4; ++i)
#pragma unroll
                for (int j = 0; j < 2; ++j)
                    acc[i][j] = __builtin_amdgcn_mfma_f32_16x16x32_bf16(
                        fa[i], fb[j], acc[i][j], 0, 0, 0);
        }
    }
#pragma unroll
    for (int i = 0; i < 4; ++i) {
        int rbase = rt * 128 + wr + i * 16 + g * 4;
        float4 bias = *reinterpret_cast<const float4*>(&bh[rbase]);
#pragma unroll
        for (int j = 0; j < 2; ++j) {
            int b = half * 64 + wc + j * 16 + l15;
            float4 v = make_float4(acc[i][j][0] + bias.x, acc[i][j][1] + bias.y,
                                   acc[i][j][2] + bias.z, acc[i][j][3] + bias.w);
            *reinterpret_cast<float4*>(
                &xwb[(size_t)(t * BB + b) * MHW + rbase]) = v;
        }
    }
}

// ---------------------------------------------------------------------------
// K_a2: a2[mi] = A[mi]·A[mi] (f32 out, 128x128), one block per mi.
// B-tile staged transposed via scalar reads (one-time cost).
// ---------------------------------------------------------------------------
__global__ __launch_bounds__(256) void k_a2(const float* __restrict__ Whh,
                                            float* __restrict__ a2) {
    int mi = blockIdx.x;
    __shared__ char lds[2 * TILE_B];
    int tid = threadIdx.x, lane = tid & 63, wid = tid >> 6;
    int l15 = lane & 15, g = lane >> 4;
    int wr = (wid >> 1) * 64, wc = (wid & 1) * 64;
    const float* Ab = Whh + (size_t)(mi * HH) * MHW + mi * HH;
    f32x4 acc[4][4] = {};
    for (int c0 = 0; c0 < 128; c0 += 64) {
        float4 vA[8];
        stage_load(vA, Ab + c0, MHW, tid);
        __syncthreads();  // prev mfma done before overwrite
        stage_write(lds, vA, tid);
        {   // transposed stage: Btile[row][kk] = A[c0+kk][row]
            int k4 = (tid & 15) * 4;
            int r0 = tid >> 4;
#pragma unroll
            for (int p = 0; p < 8; ++p) {
                int row = p * 16 + r0;
                ushort4 b;
                b.x = f2bf(Ab[(size_t)(c0 + k4 + 0) * MHW + row]);
                b.y = f2bf(Ab[(size_t)(c0 + k4 + 1) * MHW + row]);
                b.z = f2bf(Ab[(size_t)(c0 + k4 + 2) * MHW + row]);
                b.w = f2bf(Ab[(size_t)(c0 + k4 + 3) * MHW + row]);
                int off = (row * 128 + k4 * 2) ^ ((row & 7) << 4);
                *reinterpret_cast<ushort4*>(lds + TILE_B + off) = b;
            }
        }
        __syncthreads();
        mfma_tile(lds, lds + TILE_B, acc, lane, wr, wc);
    }
    float* dst = a2 + mi * 16384;
#pragma unroll
    for (int i = 0; i < 4; ++i) {
        int r0 = wr + i * 16 + g * 4;
#pragma unroll
        for (int jq = 0; jq < 4; ++jq) {
            int c = wc + jq * 16 + l15;
#pragma unroll
            for (int rr = 0; rr < 4; ++rr)
                dst[(size_t)(r0 + rr) * 128 + c] = acc[i][jq][rr];
        }
    }
}

// ---------------------------------------------------------------------------
// K_u (unchanged): xwb[t][b][mi*H+r] += sum_{j>mi} Whh[...]·h_j[b][c]
// ---------------------------------------------------------------------------
__global__ __launch_bounds__(256) void k_u(const float* __restrict__ Whh,
                                           const float* __restrict__ hprev,
                                           const unsigned short* __restrict__ hmod,
                                           float* __restrict__ xwb, int mi) {
    int k = blockIdx.x;
    int t = k << mi;
    __shared__ char lds[4 * TILE_B];
    int tid = threadIdx.x, lane = tid & 63, wid = tid >> 6;
    int wr = (wid >> 1) * 64, wc = (wid & 1) * 64;

    int ntile = 2 * (7 - mi);
    f32x4 acc[4][4] = {};

    if (k == 0) {
        auto srcs = [&](int tt, const float*& pa, const float*& ph) {
            int j = mi + 1 + (tt >> 1);
            int c0 = (tt & 1) * 64;
            pa = Whh + (size_t)(mi * HH) * MHW + j * HH + c0;
            ph = hprev + j * HH + c0;
        };
        float4 vA[8], vH[8];
        const float *pa, *ph;
        srcs(0, pa, ph);
        stage_load(vA, pa, MHW, tid);
        stage_load(vH, ph, MHW, tid);
        stage_write(lds, vA, tid);
        stage_write(lds + TILE_B, vH, tid);
        for (int tt = 0; tt < ntile; ++tt) {
            int cur = tt & 1;
            __syncthreads();
            if (tt + 1 < ntile) {
                srcs(tt + 1, pa, ph);
                stage_load(vA, pa, MHW, tid);
                stage_load(vH, ph, MHW, tid);
            }
            mfma_tile(lds + cur * 2 * TILE_B, lds + cur * 2 * TILE_B + TILE_B,
                      acc, lane, wr, wc);
            if (tt + 1 < ntile) {
                stage_write(lds + (cur ^ 1) * 2 * TILE_B, vA, tid);
                stage_write(lds + (cur ^ 1) * 2 * TILE_B + TILE_B, vH, tid);
            }
        }
    } else {
        auto srcs = [&](int tt, const float*& pa, const unsigned short*& ph) {
            int j = mi + 1 + (tt >> 1);
            int c0 = (tt & 1) * 64;
            pa = Whh + (size_t)(mi * HH) * MHW + j * HH + c0;
            int g = (t - 1) >> j;
            ph = hmod + c_hmod_off[j] + (size_t)g * BB * HH + c0;
        };
        float4 vA[8];
        uint4 vH[4];
        const float* pa;
        const unsigned short* ph;
        srcs(0, pa, ph);
        stage_load(vA, pa, MHW, tid);
        stage_load_h16(vH, ph, tid);
        stage_write(lds, vA, tid);
        stage_write_h16(lds + TILE_B, vH, tid);
        for (int tt = 0; tt < ntile; ++tt) {
            int cur = tt & 1;
            __syncthreads();
            if (tt + 1 < ntile) {
                srcs(tt + 1, pa, ph);
                stage_load(vA, pa, MHW, tid);
                stage_load_h16(vH, ph, tid);
            }
            mfma_tile(lds + cur * 2 * TILE_B, lds + cur * 2 * TILE_B + TILE_B,
                      acc, lane, wr, wc);
            if (tt + 1 < ntile) {
                stage_write(lds + (cur ^ 1) * 2 * TILE_B, vA, tid);
                stage_write_h16(lds + (cur ^ 1) * 2 * TILE_B + TILE_B, vH, tid);
            }
        }
    }
#pragma unroll
    for (int i = 0; i < 4; ++i) {
        int rbase = wr + i * 16 + (lane >> 4) * 4;
#pragma unroll
        for (int j = 0; j < 4; ++j) {
            int b = wc + j * 16 + (lane & 15);
            float4* p = reinterpret_cast<float4*>(
                &xwb[(size_t)(t * BB + b) * MHW + mi * HH + rbase]);
            float4 v = *p;
            v.x += acc[i][j][0]; v.y += acc[i][j][1];
            v.z += acc[i][j][2]; v.w += acc[i][j][3];
            *p = v;
        }
    }
}

// ---------------------------------------------------------------------------
// K_v: v_j = A·u_{2j} + u_{2j+1}, one block per pair j. Output f32 [j][b][r].
// ---------------------------------------------------------------------------
__global__ __launch_bounds__(256) void k_v(const float* __restrict__ Whh,
                                           const float* __restrict__ xwb,
                                           float* __restrict__ vbuf, int mi) {
    int j = blockIdx.x;
    int t0 = (2 * j) << mi, t1 = (2 * j + 1) << mi;
    __shared__ char lds[4 * TILE_B];
    int tid = threadIdx.x, lane = tid & 63, wid = tid >> 6;
    int l15 = lane & 15, g = lane >> 4;
    int wr = (wid >> 1) * 64, wc = (wid & 1) * 64;

    const float* Ab = Whh + (size_t)(mi * HH) * MHW + mi * HH;
    const float* Hb = xwb + (size_t)t0 * BB * MHW + mi * HH;
    float4 vA[8], vH[8];
    stage_load(vA, Ab, MHW, tid);
    stage_load(vH, Hb, MHW, tid);
    stage_write(lds, vA, tid);
    stage_write(lds + TILE_B, vH, tid);
    f32x4 acc[4][4] = {};
    for (int tt = 0; tt < 2; ++tt) {
        int cur = tt & 1;
        __syncthreads();
        if (tt == 0) {
            stage_load(vA, Ab + 64, MHW, tid);
            stage_load(vH, Hb + 64, MHW, tid);
        }
        mfma_tile(lds + cur * 2 * TILE_B, lds + cur * 2 * TILE_B + TILE_B,
                  acc, lane, wr, wc);
        if (tt == 0) {
            stage_write(lds + 2 * TILE_B, vA, tid);
            stage_write(lds + 3 * TILE_B, vH, tid);
        }
    }
#pragma unroll
    for (int i = 0; i < 4; ++i) {
        int rbase = wr + i * 16 + g * 4;
#pragma unroll
        for (int jq = 0; jq < 4; ++jq) {
            int b = wc + jq * 16 + l15;
            float4 u1 = *reinterpret_cast<const float4*>(
                &xwb[(size_t)(t1 * BB + b) * MHW + mi * HH + rbase]);
            float4 v = make_float4(acc[i][jq][0] + u1.x, acc[i][jq][1] + u1.y,
                                   acc[i][jq][2] + u1.z, acc[i][jq][3] + u1.w);
            *reinterpret_cast<float4*>(
                &vbuf[((size_t)j * BB + b) * HH + rbase]) = v;
        }
    }
}

// ---------------------------------------------------------------------------
// K_even: h_{2j} = A·h_{2j-1} + u_{2j}, one block per j. Writes hmod slot 2j.
// h_{-1} = hprev (f32) for j==0, else hmod slot 2j-1 (bf16).
// ---------------------------------------------------------------------------
__global__ __launch_bounds__(256) void k_even(const float* __restrict__ Whh,
                                              const float* __restrict__ hprev,
                                              const float* __restrict__ xwb,
                                              unsigned short* __restrict__ hmod,
                                              int mi) {
    int j = blockIdx.x;
    int t0 = (2 * j) << mi;
    __shared__ char lds[4 * TILE_B];
    int tid = threadIdx.x, lane = tid & 63, wid = tid >> 6;
    int l15 = lane & 15, g = lane >> 4;
    int wr = (wid >> 1) * 64, wc = (wid & 1) * 64;

    const float* Ab = Whh + (size_t)(mi * HH) * MHW + mi * HH;
    f32x4 acc[4][4] = {};
    if (j == 0) {
        const float* Hb = hprev + mi * HH;
        float4 vA[8], vH[8];
        stage_load(vA, Ab, MHW, tid);
        stage_load(vH, Hb, MHW, tid);
        stage_write(lds, vA, tid);
        stage_write(lds + TILE_B, vH, tid);
        for (int tt = 0; tt < 2; ++tt) {
            int cur = tt & 1;
            __syncthreads();
            if (tt == 0) {
                stage_load(vA, Ab + 64, MHW, tid);
                stage_load(vH, Hb + 64, MHW, tid);
            }
            mfma_tile(lds + cur * 2 * TILE_B, lds + cur * 2 * TILE_B + TILE_B,
                      acc, lane, wr, wc);
            if (tt == 0) {
                stage_write(lds + 2 * TILE_B, vA, tid);
                stage_write(lds + 3 * TILE_B, vH, tid);
            }
        }
    } else {
        const unsigned short* Hb =
            hmod + c_hmod_off[mi] + (size_t)(2 * j - 1) * BB * HH;
        float4 vA[8];
        uint4 vH[4];
        stage_load(vA, Ab, MHW, tid);
        stage_load_h16(vH, Hb, tid);
        stage_write(lds, vA, tid);
        stage_write_h16(lds + TILE_B, vH, tid);
        for (int tt = 0; tt < 2; ++tt) {
            int cur = tt & 1;
            __syncthreads();
            if (tt == 0) {
                stage_load(vA, Ab + 64, MHW, tid);
                stage_load_h16(vH, Hb + 64, tid);
            }
            mfma_tile(lds + cur * 2 * TILE_B, lds + cur * 2 * TILE_B + TILE_B,
                      acc, lane, wr, wc);
            if (tt == 0) {
                stage_write(lds + 2 * TILE_B, vA, tid);
                stage_write_h16(lds + 3 * TILE_B, vH, tid);
            }
        }
    }
#pragma unroll
    for (int i = 0; i < 4; ++i) {
        int rbase = wr + i * 16 + g * 4;
#pragma unroll
        for (int jq = 0; jq < 4; ++jq) {
            int b = wc + jq * 16 + l15;
            float4 u0 = *reinterpret_cast<const float4*>(
                &xwb[(size_t)(t0 * BB + b) * MHW + mi * HH + rbase]);
            uint2 pk;
            pk.x = pack2(acc[i][jq][0] + u0.x, acc[i][jq][1] + u0.y);
            pk.y = pack2(acc[i][jq][2] + u0.z, acc[i][jq][3] + u0.w);
            *reinterpret_cast<uint2*>(
                &hmod[c_hmod_off[mi] + ((size_t)(2 * j) * BB + b) * HH + rbase]) = pk;
        }
    }
}

// ---------------------------------------------------------------------------
// K_phase v7: wave-specialized scan with A^2 over Tm/2 steps (odd slots).
// grid 8 blocks (16 batches each), waves {0,1}: compute, 2: u-prod, 3: storer.
// ---------------------------------------------------------------------------
#define SYNC_LDS()                                              \
    do {                                                        \
        asm volatile("s_waitcnt lgkmcnt(0)" ::: "memory");      \
        __builtin_amdgcn_sched_barrier(0);                      \
        __builtin_amdgcn_s_barrier();                           \
        __builtin_amdgcn_sched_barrier(0);                      \
    } while (0)
#define SYNC_VM24()                                             \
    do {                                                        \
        asm volatile("s_waitcnt vmcnt(24)" ::: "memory");       \
        __builtin_amdgcn_sched_barrier(0);                      \
        __builtin_amdgcn_s_barrier();                           \
        __builtin_amdgcn_sched_barrier(0);                      \
    } while (0)

__global__ __launch_bounds__(256) void k_phase(const float* __restrict__ a2,
                                               const float* __restrict__ hprev,
                                               const float* __restrict__ vbuf,
                                               unsigned short* __restrict__ hmod,
                                               int mi) {
    int b0 = blockIdx.x * 16;
    int tid = threadIdx.x, lane = tid & 63, wid = tid >> 6;
    int l15 = lane & 15, g = lane >> 4;
    __shared__ char sH[2][4096];   // [buf][b][r] bf16, swizzled
    __shared__ char sU[8][8192];   // v ring: [slot][r/4][b][4xf32], linear
    int Tm_s = 128 >> mi;          // folded step count

    if (wid < 2) {
        // ================= compute waves =================
        bf16x8 Af[4][4];
        {
            const float* Ab = a2 + mi * 16384;
#pragma unroll
            for (int mm = 0; mm < 4; ++mm) {
                const float* row = Ab + (size_t)(64 * wid + mm * 16 + l15) * 128;
#pragma unroll
                for (int kf = 0; kf < 4; ++kf) {
                    float4 v0 = *reinterpret_cast<const float4*>(row + kf * 32 + g * 8);
                    float4 v1 = *reinterpret_cast<const float4*>(row + kf * 32 + g * 8 + 4);
                    bf16x8 u;
                    u[0] = (__bf16)v0.x; u[1] = (__bf16)v0.y;
                    u[2] = (__bf16)v0.z; u[3] = (__bf16)v0.w;
                    u[4] = (__bf16)v1.x; u[5] = (__bf16)v1.y;
                    u[6] = (__bf16)v1.z; u[7] = (__bf16)v1.w;
                    Af[mm][kf] = u;
                }
            }
        }
        // initial H = h_{-1} into buf 0
#pragma unroll
        for (int p = 0; p < 2; ++p) {
            int tt = tid + p * 128;
            int b = tt >> 4, r8 = (tt & 15) * 8;
            const float* hp = hprev + (size_t)(b0 + b) * MHW + mi * HH + r8;
            float4 v0 = *reinterpret_cast<const float4*>(hp);
            float4 v1 = *reinterpret_cast<const float4*>(hp + 4);
            uint4 pk;
            pk.x = pack2(v0.x, v0.y); pk.y = pack2(v0.z, v0.w);
            pk.z = pack2(v1.x, v1.y); pk.w = pack2(v1.z, v1.w);
            int off = (b * 256 + r8 * 2) ^ ((b & 7) << 4);
            *reinterpret_cast<uint4*>(&sH[0][0] + off) = pk;
        }
        int roff[4], woff[4], uoff[4];
#pragma unroll
        for (int kf = 0; kf < 4; ++kf)
            roff[kf] = (l15 * 256 + kf * 64 + g * 16) ^ ((l15 & 7) << 4);
#pragma unroll
        for (int mm = 0; mm < 4; ++mm) {
            woff[mm] = (l15 * 256 + (64 * wid + mm * 16 + g * 4) * 2) ^ ((l15 & 7) << 4);
            uoff[mm] = (16 * wid + 4 * mm + g) * 256 + l15 * 16;
        }
        SYNC_LDS();

        for (int K = 0; K < Tm_s; ++K) {
            int cur = K & 1;
            const char* ub = &sU[K & 7][0];
            f32x4 acc[4], acc2[4];
#pragma unroll
            for (int mm = 0; mm < 4; ++mm) {
                acc[mm] = *reinterpret_cast<const f32x4*>(ub + uoff[mm]);
                acc2[mm] = (f32x4){0.f, 0.f, 0.f, 0.f};
            }
            bf16x8 Bf[4];
#pragma unroll
            for (int kf = 0; kf < 4; ++kf)
                Bf[kf] = *reinterpret_cast<const bf16x8*>(&sH[cur][0] + roff[kf]);
#pragma unroll
            for (int mm = 0; mm < 4; ++mm) {
                acc[mm] = __builtin_amdgcn_mfma_f32_16x16x32_bf16(
                    Af[mm][0], Bf[0], acc[mm], 0, 0, 0);
                acc2[mm] = __builtin_amdgcn_mfma_f32_16x16x32_bf16(
                    Af[mm][2], Bf[2], acc2[mm], 0, 0, 0);
                acc[mm] = __builtin_amdgcn_mfma_f32_16x16x32_bf16(
                    Af[mm][1], Bf[1], acc[mm], 0, 0, 0);
                acc2[mm] = __builtin_amdgcn_mfma_f32_16x16x32_bf16(
                    Af[mm][3], Bf[3], acc2[mm], 0, 0, 0);
            }
#pragma unroll
            for (int mm = 0; mm < 4; ++mm) {
                acc[mm] += acc2[mm];
                bf16x4 pk;
                pk[0] = (__bf16)acc[mm][0]; pk[1] = (__bf16)acc[mm][1];
                pk[2] = (__bf16)acc[mm][2]; pk[3] = (__bf16)acc[mm][3];
                *reinterpret_cast<bf16x4*>(&sH[cur ^ 1][0] + woff[mm]) = pk;
            }
            SYNC_LDS();
        }
    } else if (wid == 2) {
        // ================= v producer =================
        const float* ubase = vbuf + (size_t)(b0 + l15) * HH + g * 4;
#pragma unroll
        for (int q = 0; q < 4; ++q) {  // prologue: slots 0..3
            int jj = min(q, Tm_s - 1);
            const float* pt = ubase + (size_t)jj * BB * HH;
#pragma unroll
            for (int p = 0; p < 8; ++p)
                gld_lds16(pt + p * 16, &sU[q][0] + p * 1024);
        }
        SYNC_VM24();
        for (int K = 0; K < Tm_s; ++K) {
            int jj = min(K + 4, Tm_s - 1);
            int slot = (K + 4) & 7;
            const float* pt = ubase + (size_t)jj * BB * HH;
#pragma unroll
            for (int p = 0; p < 8; ++p)
                gld_lds16(pt + p * 16, &sU[slot][0] + p * 1024);
            SYNC_VM24();
        }
        asm volatile("s_waitcnt vmcnt(0)" ::: "memory");
    } else {
        // ================= h storer (odd slots 2K+1) =================
        int bq = lane >> 2;
        int rr = (lane & 3) * 32;
        unsigned short* hm =
            hmod + c_hmod_off[mi] + (size_t)(b0 + bq) * HH + rr;
        int soff[4];
#pragma unroll
        for (int c = 0; c < 4; ++c)
            soff[c] = (bq * 256 + (rr + c * 8) * 2) ^ ((bq & 7) << 4);
        SYNC_LDS();
        for (int K = 0; K < Tm_s; ++K) {
            if (K >= 1) {
                uint4 h[4];
#pragma unroll
                for (int c = 0; c < 4; ++c)
                    h[c] = *reinterpret_cast<const uint4*>(&sH[K & 1][0] + soff[c]);
                unsigned short* dst = hm + (size_t)(2 * K - 1) * BB * HH;
#pragma unroll
                for (int c = 0; c < 4; ++c)
                    *reinterpret_cast<uint4*>(dst + c * 8) = h[c];
            }
            SYNC_LDS();
        }
        {  // final: step Tm_s-1 -> slot 2*Tm_s-1 = Tm-1
            uint4 h[4];
#pragma unroll
            for (int c = 0; c < 4; ++c)
                h[c] = *reinterpret_cast<const uint4*>(&sH[Tm_s & 1][0] + soff[c]);
            unsigned short* dst = hm + (size_t)(2 * Tm_s - 1) * BB * HH;
#pragma unroll
            for (int c = 0; c < 4; ++c)
                *reinterpret_cast<uint4*>(dst + c * 8) = h[c];
        }
    }
}

// ---------------------------------------------------------------------------
// K_out: out[t][b][j*H + h] = bf2f(Hmod[j][t>>j][b][h]); h_last for t==T-1
// ---------------------------------------------------------------------------
__global__ __launch_bounds__(256) void k_out(const unsigned short* __restrict__ hmod,
                                             float* __restrict__ out) {
    int b = blockIdx.x, t = blockIdx.y;
    int tid = threadIdx.x;
    int i = tid * 4;
    int j = i >> 7;
    int k = t >> j;
    ushort4 h = *reinterpret_cast<const ushort4*>(
        &hmod[c_hmod_off[j] + ((size_t)k * BB + b) * HH + (i & 127)]);
    float4 v = make_float4(bf2f(h.x), bf2f(h.y), bf2f(h.z), bf2f(h.w));
    *reinterpret_cast<float4*>(&out[((size_t)t * BB + b) * MHW + i]) = v;
    if (t == TT - 1) {
        *reinterpret_cast<float4*>(
            &out[(size_t)TT * BB * MHW + (size_t)b * MHW + i]) = v;
    }
}

// ---------------------------------------------------------------------------
extern "C" void kernel_launch(void* const* d_in, const int* in_sizes, int n_in,
                              void* d_out, int out_size, void* d_ws, size_t ws_size,
                              hipStream_t stream) {
    const float* x = (const float*)d_in[0];
    const float* hprev = (const float*)d_in[1];
    const float* Wxh = (const float*)d_in[2];
    const float* Whh = (const float*)d_in[3];
    const float* bh = (const float*)d_in[4];
    float* out = (float*)d_out;

    float* xwb = out;                              // scratch in d_out
    unsigned short* hmod = (unsigned short*)d_ws;  // bf16, 16.7 MB
    float* vbuf = (float*)((char*)d_ws + 16711680);        // 8.4 MB, shared
    float* a2 = (float*)((char*)d_ws + 16711680 + 8388608);  // 512 KB

    k_xw<<<dim3(1020), 256, 0, stream>>>(x, Wxh, bh, xwb);
    k_a2<<<dim3(8), 256, 0, stream>>>(Whh, a2);

    for (int mi = 7; mi >= 0; --mi) {
        if (mi < 7)
            k_u<<<dim3(TT >> mi), 256, 0, stream>>>(Whh, hprev, hmod, xwb, mi);
        k_v<<<dim3(128 >> mi), 256, 0, stream>>>(Whh, xwb, vbuf, mi);
        k_phase<<<8, 256, 0, stream>>>(a2, hprev, vbuf, hmod, mi);
        k_even<<<dim3(128 >> mi), 256, 0, stream>>>(Whh, hprev, xwb, hmod, mi);
    }

    k_out<<<dim3(128, 256), 256, 0, stream>>>(hmod, out);
}